// Round 11
// baseline (375.659 us; speedup 1.0000x reference)
//
#include <hip/hip_runtime.h>
#include <math.h>

#define NROWS 65536
#define DDIM 2048
#define NEXP 64
#define TOPK 8

constexpr int NSTEP = 64;        // k-steps of 32
constexpr float THR = 3e-4f;     // ambiguity gap threshold (split-bf16 err rms ~4e-6)
constexpr int WFRAG_STEP = 4096; // shorts per k-step: [hl 2][ct 4][lane 64][j 8]

typedef short bf16x8 __attribute__((ext_vector_type(8)));
typedef float f32x4 __attribute__((ext_vector_type(4)));

__device__ inline unsigned short bfround(float f) {
    union { float f; unsigned u; } v; v.f = f;
    unsigned r = (v.u + 0x7fffu + ((v.u >> 16) & 1u)) >> 16;   // RNE
    return (unsigned short)r;
}
__device__ inline float bf2f(unsigned short h) {
    union { unsigned u; float f; } v; v.u = ((unsigned)h) << 16;
    return v.f;
}
__device__ inline void cvt8(const float4& A, const float4& B, bf16x8& h, bf16x8& l) {
    float f[8] = {A.x, A.y, A.z, A.w, B.x, B.y, B.z, B.w};
#pragma unroll
    for (int j = 0; j < 8; ++j) {
        unsigned short hh = bfround(f[j]);
        h[j] = (short)hh;
        l[j] = (short)bfround(f[j] - bf2f(hh));
    }
}

// One-shot: W fp32 [64][2048] -> bf16 hi/lo in MFMA B-fragment order.
// wfrag[t][hl][ct][lane][j]; expert e=ct*16+(lane&15), k=t*32+(lane>>4)*8+j.
__global__ __launch_bounds__(256)
void prep_kernel(const float* __restrict__ W, short* __restrict__ wfrag)
{
    const int t = blockIdx.x;           // 0..63
    const int tid = threadIdx.x;
    const int ct = tid >> 6, lane = tid & 63;
    const int e = ct * 16 + (lane & 15);
    const int k = t * 32 + (lane >> 4) * 8;
    const float* wp = W + (size_t)e * DDIM + k;
    float4 a = *reinterpret_cast<const float4*>(wp);
    float4 b = *reinterpret_cast<const float4*>(wp + 4);
    bf16x8 h, l;
    cvt8(a, b, h, l);
    short* base = wfrag + (size_t)t * WFRAG_STEP;
    *reinterpret_cast<bf16x8*>(base + (ct * 64 + lane) * 8) = h;          // hl=0
    *reinterpret_cast<bf16x8*>(base + 2048 + (ct * 64 + lane) * 8) = l;   // hl=1
}

// Lean split-bf16 MFMA GEMM: 1024 blocks x 4 waves x 16 rows, barrier-free,
// LDS-free, B direct from wfrag (L1/L2-hot). Occupancy lesson (r10): 512
// blocks grid-limited us to 2 waves/SIMD; 1024 blocks + VGPR<=128 gives 4.
// launch_bounds cap = 256/min_waves (r3/r4): (256,2) -> 128 VGPRs.
__global__ __launch_bounds__(256, 2)
void gemm_kernel(const float* __restrict__ x, const short* __restrict__ wfrag,
                 float* __restrict__ logits)
{
    const int tid = threadIdx.x;
    const int w = tid >> 6;
    const int lane = tid & 63;
    const int g = lane >> 4;         // k-subgroup (A) / row subgroup (C)
    const int c = lane & 15;         // A row offset / C col offset
    const int row0 = blockIdx.x * 64 + w * 16;
    const float* xr = x + (size_t)(row0 + c) * DDIM + g * 8;

    f32x4 acc[4];
#pragma unroll
    for (int ct = 0; ct < 4; ++ct) acc[ct] = (f32x4){0.f, 0.f, 0.f, 0.f};

    float4 xa0 = *reinterpret_cast<const float4*>(xr);
    float4 xa1 = *reinterpret_cast<const float4*>(xr + 4);
    float4 xb0, xb1;

    for (int t = 0; t < NSTEP; ++t) {
        const short* wt = wfrag + (size_t)t * WFRAG_STEP;
        bf16x8 bh[4], bl[4];
#pragma unroll
        for (int ct = 0; ct < 4; ++ct) {
            bh[ct] = *reinterpret_cast<const bf16x8*>(wt + (ct * 64 + lane) * 8);
            bl[ct] = *reinterpret_cast<const bf16x8*>(wt + 2048 + (ct * 64 + lane) * 8);
        }
        const int kn = (t + 1) * 32;
        if (t + 1 < NSTEP) {
            xb0 = *reinterpret_cast<const float4*>(xr + kn);
            xb1 = *reinterpret_cast<const float4*>(xr + kn + 4);
        }
        bf16x8 ah, al;
        cvt8(xa0, xa1, ah, al);
        // 3-term split-bf16: x*w = xh*wh + xh*wl + xl*wh (xl*wl ~4e-6, dropped)
#pragma unroll
        for (int ct = 0; ct < 4; ++ct) {
            acc[ct] = __builtin_amdgcn_mfma_f32_16x16x32_bf16(ah, bh[ct], acc[ct], 0, 0, 0);
            acc[ct] = __builtin_amdgcn_mfma_f32_16x16x32_bf16(ah, bl[ct], acc[ct], 0, 0, 0);
            acc[ct] = __builtin_amdgcn_mfma_f32_16x16x32_bf16(al, bh[ct], acc[ct], 0, 0, 0);
        }
        xa0 = xb0; xa1 = xb1;
    }

    // C/D layout (m89): acc[ct][reg] = C[row0 + g*4 + reg][ct*16 + c]
#pragma unroll
    for (int ct = 0; ct < 4; ++ct)
#pragma unroll
        for (int reg = 0; reg < 4; ++reg)
            logits[(size_t)(row0 + g * 4 + reg) * NEXP + ct * 16 + c] = acc[ct][reg];
}

// Epilogue: one wave per row, lane == expert. Top-9 extraction, softmax/psum
// (pcol lane-local), z-loss, gates; flagged rows get INLINE fp64 candidate
// recheck (wave already holds the row's logits — no lists, no second kernel).
__global__ __launch_bounds__(256, 1)
void epilogue_kernel(const float* __restrict__ x, const float* __restrict__ W,
                     const float* __restrict__ logits,
                     float* __restrict__ out_idx, float* __restrict__ out_gate,
                     float* __restrict__ g_psum, float* __restrict__ g_freq,
                     float* __restrict__ g_zsum)
{
    __shared__ float psum_s[NEXP];
    __shared__ float fcnt_s[NEXP];
    __shared__ float zsq_s;
    const int tid = threadIdx.x;
    const int w = tid >> 6;
    const int lane = tid & 63;
    if (tid < NEXP) { psum_s[tid] = 0.f; fcnt_s[tid] = 0.f; }
    if (tid == 0) zsq_s = 0.f;
    __syncthreads();

    const int wi = blockIdx.x * 4 + w;   // wave id 0..8191
    float pcol = 0.f, zacc = 0.f;

    for (int r8 = 0; r8 < 8; ++r8) {
        const int row = wi + r8 * 8192;
        const float lg = logits[(size_t)row * NEXP + lane];

        // top-9 extraction (fp32, lowest-index tie-break == lax.top_k)
        float vv = lg;
        float tv[9]; int ti[9];
#pragma unroll
        for (int p = 0; p < 9; ++p) {
            float bv = vv; int bgi = lane;
#pragma unroll
            for (int m = 1; m < 64; m <<= 1) {
                float ov = __shfl_xor(bv, m, 64);
                int ogi = __shfl_xor(bgi, m, 64);
                if (ov > bv || (ov == bv && ogi < bgi)) { bv = ov; bgi = ogi; }
            }
            tv[p] = bv; ti[p] = bgi;
            if (lane == bgi) vv = -3.4e38f;
        }

        // softmax probs: lane owns its expert -> pcol is register-local
        const float m0 = tv[0];
        float pe = expf(lg - m0);
        float s = pe;
#pragma unroll
        for (int m = 1; m < 64; m <<= 1) s += __shfl_xor(s, m, 64);
        pcol += pe / s;

        if (lane == 0) {   // z-loss: logaddexp(lse, log(1e-5))^2
            float lsef = m0 + logf(s);
            const float lb = -11.512925464970229f;
            float mx = fmaxf(lsef, lb), mn = fminf(lsef, lb);
            float z = mx + log1pf(expf(mn - mx));
            zacc += z * z;
        }

        float mg = 3.4e38f;
#pragma unroll
        for (int p = 0; p < 8; ++p) mg = fminf(mg, tv[p] - tv[p + 1]);
        const size_t base = (size_t)row * TOPK;

        if (mg >= THR) {                 // unambiguous (normal path)
            float gs = 0.f;
#pragma unroll
            for (int p = 0; p < 8; ++p) gs += expf(tv[p] - m0);
            if (lane < 8) {
                float mytv = tv[0]; int myti = ti[0];
#pragma unroll
                for (int p = 1; p < 8; ++p)
                    if (lane == p) { mytv = tv[p]; myti = ti[p]; }
                out_idx[base + lane] = (float)myti;
                out_gate[base + lane] = expf(mytv - m0) / gs;
                atomicAdd(&fcnt_s[myti], 1.f);
            }
        } else {                         // inline fp64 recheck (~3.5% of rows)
            const bool cand = (lg >= tv[8] - THR);   // only these can be top-8
            unsigned long long cm = __ballot(cand);
            const float* xrw = x + (size_t)row * DDIM;
            float4 xv[8];
#pragma unroll
            for (int j = 0; j < 8; ++j)
                xv[j] = *reinterpret_cast<const float4*>(xrw + j * 256 + lane * 4);

            double myD = -HUGE_VAL;
            unsigned long long m2 = cm;
            while (m2) {                 // serial coalesced fp64 dots
                const int e = (int)__ffsll((unsigned long long)m2) - 1;
                m2 &= (m2 - 1);
                const float* wrp = W + (size_t)e * DDIM;
                double p0 = 0.0, p1 = 0.0, p2 = 0.0, p3 = 0.0;
#pragma unroll
                for (int j = 0; j < 8; ++j) {
                    float4 wv = *reinterpret_cast<const float4*>(wrp + j * 256 + lane * 4);
                    p0 = fma((double)xv[j].x, (double)wv.x, p0);
                    p1 = fma((double)xv[j].y, (double)wv.y, p1);
                    p2 = fma((double)xv[j].z, (double)wv.z, p2);
                    p3 = fma((double)xv[j].w, (double)wv.w, p3);
                }
                double sd = (p0 + p1) + (p2 + p3);
#pragma unroll
                for (int m = 1; m < 64; m <<= 1) sd += __shfl_xor(sd, m, 64);
                if (lane == e) myD = sd;
            }

            double v = cand ? myD : -HUGE_VAL;
            double tvd[8]; int ti8[8];
#pragma unroll
            for (int p = 0; p < 8; ++p) {
                double bv = v; int bgi = lane;
#pragma unroll
                for (int m = 1; m < 64; m <<= 1) {
                    double ov = __shfl_xor(bv, m, 64);
                    int ogi = __shfl_xor(bgi, m, 64);
                    if (ov > bv || (ov == bv && ogi < bgi)) { bv = ov; bgi = ogi; }
                }
                tvd[p] = bv; ti8[p] = bgi;
                if (lane == bgi) v = -HUGE_VAL;
            }
            const double m0d = tvd[0];
            double gsum = 0.0, ge[8];
#pragma unroll
            for (int j = 0; j < 8; ++j) { ge[j] = exp(tvd[j] - m0d); gsum += ge[j]; }
            if (lane < 8) {
                double myge = ge[0]; int myti = ti8[0];
#pragma unroll
                for (int j = 1; j < 8; ++j)
                    if (lane == j) { myge = ge[j]; myti = ti8[j]; }
                out_idx[base + lane] = (float)myti;
                out_gate[base + lane] = (float)(myge / gsum);
                atomicAdd(&fcnt_s[myti], 1.f);
            }
        }
    }

    // block-combine, then one global atomic per expert per block
    atomicAdd(&psum_s[lane], pcol);
    if (lane == 0) atomicAdd(&zsq_s, zacc);
    __syncthreads();
    if (tid < NEXP) {
        atomicAdd(&g_psum[tid], psum_s[tid]);
        atomicAdd(&g_freq[tid], fcnt_s[tid]);
    }
    if (tid == 0) atomicAdd(g_zsum, zsq_s);
}

__global__ void finalize_kernel(const float* __restrict__ g_psum,
                                const float* __restrict__ g_freq,
                                const float* __restrict__ g_zsum,
                                float* __restrict__ out_loss)
{
    const int lane = threadIdx.x & 63;
    float p = g_psum[lane], f = g_freq[lane];
    float sp = p, sf = f;
#pragma unroll
    for (int m = 1; m < 64; m <<= 1) { sp += __shfl_xor(sp, m, 64); sf += __shfl_xor(sf, m, 64); }
    sp = fmaxf(sp, 1e-12f);
    sf = fmaxf(sf, 1e-12f);
    float term = (p / sp) * (f / sf);
#pragma unroll
    for (int m = 1; m < 64; m <<= 1) term += __shfl_xor(term, m, 64);
    if (lane == 0)
        out_loss[0] = (float)NEXP * term + 0.1f * (g_zsum[0] / (float)NROWS);
}

extern "C" void kernel_launch(void* const* d_in, const int* in_sizes, int n_in,
                              void* d_out, int out_size, void* d_ws, size_t ws_size,
                              hipStream_t stream)
{
    const float* x = (const float*)d_in[0];
    const float* W = (const float*)d_in[1];
    float* out = (float*)d_out;
    float* out_idx  = out;                            // [65536*8] indices as float
    float* out_gate = out + (size_t)NROWS * TOPK;     // [65536*8] gates
    float* out_loss = out + (size_t)2 * NROWS * TOPK; // [1] loss

    // ws layout (floats): [0..63] psum | [64..127] freq | [128] zsum |
    //   [256..) logits 65536x64 (16 MB) | then wfrag (512 KB, 16B-aligned)
    float* acc    = (float*)d_ws;
    float* logits = (float*)d_ws + 256;
    short* wfrag  = (short*)((float*)d_ws + 256 + (size_t)NROWS * NEXP);
    hipMemsetAsync(d_ws, 0, 129 * sizeof(float), stream);

    prep_kernel<<<NSTEP, 256, 0, stream>>>(W, wfrag);
    gemm_kernel<<<NROWS / 64, 256, 0, stream>>>(x, wfrag, logits);
    epilogue_kernel<<<2048, 256, 0, stream>>>(x, W, logits, out_idx, out_gate,
                                              acc, acc + NEXP, acc + 2 * NEXP);
    finalize_kernel<<<1, 64, 0, stream>>>(acc, acc + NEXP, acc + 2 * NEXP, out_loss);
}

// Round 12
// 342.123 us; speedup vs baseline: 1.0980x; 1.0980x over previous
//
#include <hip/hip_runtime.h>
#include <math.h>

#define NROWS 65536
#define DDIM 2048
#define NEXP 64
#define TOPK 8

constexpr int NSTEP = 64;        // k-steps of 32
constexpr float THR = 3e-4f;     // ambiguity gap threshold (split-bf16 err rms ~4e-6)
constexpr int WFRAG_STEP = 4096; // shorts per k-step: [hl 2][ct 4][lane 64][j 8]

typedef short bf16x8 __attribute__((ext_vector_type(8)));
typedef float f32x4 __attribute__((ext_vector_type(4)));

__device__ inline unsigned short bfround(float f) {
    union { float f; unsigned u; } v; v.f = f;
    unsigned r = (v.u + 0x7fffu + ((v.u >> 16) & 1u)) >> 16;   // RNE
    return (unsigned short)r;
}
__device__ inline float bf2f(unsigned short h) {
    union { unsigned u; float f; } v; v.u = ((unsigned)h) << 16;
    return v.f;
}
__device__ inline void cvt8(const float4& A, const float4& B, bf16x8& h, bf16x8& l) {
    float f[8] = {A.x, A.y, A.z, A.w, B.x, B.y, B.z, B.w};
#pragma unroll
    for (int j = 0; j < 8; ++j) {
        unsigned short hh = bfround(f[j]);
        h[j] = (short)hh;
        l[j] = (short)bfround(f[j] - bf2f(hh));
    }
}

// One-shot: W fp32 [64][2048] -> bf16 hi/lo in MFMA B-fragment order.
// wfrag[t][hl][ct][lane][j]; expert e=ct*16+(lane&15), k=t*32+(lane>>4)*8+j.
__global__ __launch_bounds__(256)
void prep_kernel(const float* __restrict__ W, short* __restrict__ wfrag)
{
    const int t = blockIdx.x;           // 0..63
    const int tid = threadIdx.x;
    const int ct = tid >> 6, lane = tid & 63;
    const int e = ct * 16 + (lane & 15);
    const int k = t * 32 + (lane >> 4) * 8;
    const float* wp = W + (size_t)e * DDIM + k;
    float4 a = *reinterpret_cast<const float4*>(wp);
    float4 b = *reinterpret_cast<const float4*>(wp + 4);
    bf16x8 h, l;
    cvt8(a, b, h, l);
    short* base = wfrag + (size_t)t * WFRAG_STEP;
    *reinterpret_cast<bf16x8*>(base + (ct * 64 + lane) * 8) = h;          // hl=0
    *reinterpret_cast<bf16x8*>(base + 2048 + (ct * 64 + lane) * 8) = l;   // hl=1
}

// Split-bf16 MFMA GEMM, r12: LDS-staged B (r5's proven latency-hiding
// structure: stage-ahead + 1 barrier/step) x r11's grid shape (1024 blocks,
// 16 rows/wave) for 4 waves/SIMD. r10/r11 lesson: global-B with no barrier
// is L2-latency-bound (no prefetch, no lockstep L1 sharing). Slim kernel
// (GEMM + logits dump only) to fit the (256,2)=128 VGPR cap without spill.
__global__ __launch_bounds__(256, 2)
void gemm_kernel(const float* __restrict__ x, const short* __restrict__ wfrag,
                 float* __restrict__ logits)
{
    __shared__ __align__(16) short Bfrag[2][2][4][64][8];   // 16 KB

    const int tid = threadIdx.x;
    const int w = tid >> 6;
    const int lane = tid & 63;
    const int g = lane >> 4;         // k-subgroup (A) / row subgroup (C)
    const int c = lane & 15;         // A row offset / C col offset
    const int row0 = blockIdx.x * 64 + w * 16;
    const float* xr = x + (size_t)(row0 + c) * DDIM + g * 8;

    // staging role: thread t copies 16B hi + 16B lo for (expert se, k-chunk skg)
    const int se = tid >> 2, skg = tid & 3;
    const int sct = se >> 4;
    const int slane = (se & 15) + (skg << 4);
    const int soff = (sct * 64 + slane) * 8;

    auto stageB = [&](int t, int buf) {
        const short* src = wfrag + (size_t)t * WFRAG_STEP + soff;
        *reinterpret_cast<bf16x8*>(&Bfrag[buf][0][sct][slane][0]) =
            *reinterpret_cast<const bf16x8*>(src);
        *reinterpret_cast<bf16x8*>(&Bfrag[buf][1][sct][slane][0]) =
            *reinterpret_cast<const bf16x8*>(src + 2048);
    };

    f32x4 acc[4];
#pragma unroll
    for (int ct = 0; ct < 4; ++ct) acc[ct] = (f32x4){0.f, 0.f, 0.f, 0.f};

    float4 xa0 = *reinterpret_cast<const float4*>(xr);
    float4 xa1 = *reinterpret_cast<const float4*>(xr + 4);
    float4 xb0, xb1;
    stageB(0, 0);
    __syncthreads();

    for (int t = 0; t < NSTEP; ++t) {
        const int buf = t & 1;
        const int kn = (t + 1) * 32;
        if (t + 1 < NSTEP) {                 // prefetch next: A->regs, B->LDS
            xb0 = *reinterpret_cast<const float4*>(xr + kn);
            xb1 = *reinterpret_cast<const float4*>(xr + kn + 4);
            stageB(t + 1, buf ^ 1);
        }
        bf16x8 ah, al;
        cvt8(xa0, xa1, ah, al);
        // 3-term split-bf16: x*w = xh*wh + xh*wl + xl*wh (xl*wl ~4e-6, dropped)
#pragma unroll
        for (int ct = 0; ct < 4; ++ct) {
            bf16x8 bh = *reinterpret_cast<const bf16x8*>(&Bfrag[buf][0][ct][lane][0]);
            bf16x8 bl = *reinterpret_cast<const bf16x8*>(&Bfrag[buf][1][ct][lane][0]);
            acc[ct] = __builtin_amdgcn_mfma_f32_16x16x32_bf16(ah, bh, acc[ct], 0, 0, 0);
            acc[ct] = __builtin_amdgcn_mfma_f32_16x16x32_bf16(ah, bl, acc[ct], 0, 0, 0);
            acc[ct] = __builtin_amdgcn_mfma_f32_16x16x32_bf16(al, bh, acc[ct], 0, 0, 0);
        }
        xa0 = xb0; xa1 = xb1;
        __syncthreads();                     // buf^1 writes complete
    }

    // C/D layout (m89): acc[ct][reg] = C[row0 + g*4 + reg][ct*16 + c]
#pragma unroll
    for (int ct = 0; ct < 4; ++ct)
#pragma unroll
        for (int reg = 0; reg < 4; ++reg)
            logits[(size_t)(row0 + g * 4 + reg) * NEXP + ct * 16 + c] = acc[ct][reg];
}

// Epilogue: one wave per row, lane == expert. Top-9 extraction, softmax/psum
// (pcol lane-local), z-loss, gates; flagged rows get INLINE fp64 candidate
// recheck (wave already holds the row's logits — no lists, no second kernel).
__global__ __launch_bounds__(256, 1)
void epilogue_kernel(const float* __restrict__ x, const float* __restrict__ W,
                     const float* __restrict__ logits,
                     float* __restrict__ out_idx, float* __restrict__ out_gate,
                     float* __restrict__ g_psum, float* __restrict__ g_freq,
                     float* __restrict__ g_zsum)
{
    __shared__ float psum_s[NEXP];
    __shared__ float fcnt_s[NEXP];
    __shared__ float zsq_s;
    const int tid = threadIdx.x;
    const int w = tid >> 6;
    const int lane = tid & 63;
    if (tid < NEXP) { psum_s[tid] = 0.f; fcnt_s[tid] = 0.f; }
    if (tid == 0) zsq_s = 0.f;
    __syncthreads();

    const int wi = blockIdx.x * 4 + w;   // wave id 0..8191
    float pcol = 0.f, zacc = 0.f;

    for (int r8 = 0; r8 < 8; ++r8) {
        const int row = wi + r8 * 8192;
        const float lg = logits[(size_t)row * NEXP + lane];

        // top-9 extraction (fp32, lowest-index tie-break == lax.top_k)
        float vv = lg;
        float tv[9]; int ti[9];
#pragma unroll
        for (int p = 0; p < 9; ++p) {
            float bv = vv; int bgi = lane;
#pragma unroll
            for (int m = 1; m < 64; m <<= 1) {
                float ov = __shfl_xor(bv, m, 64);
                int ogi = __shfl_xor(bgi, m, 64);
                if (ov > bv || (ov == bv && ogi < bgi)) { bv = ov; bgi = ogi; }
            }
            tv[p] = bv; ti[p] = bgi;
            if (lane == bgi) vv = -3.4e38f;
        }

        // softmax probs: lane owns its expert -> pcol is register-local
        const float m0 = tv[0];
        float pe = expf(lg - m0);
        float s = pe;
#pragma unroll
        for (int m = 1; m < 64; m <<= 1) s += __shfl_xor(s, m, 64);
        pcol += pe / s;

        if (lane == 0) {   // z-loss: logaddexp(lse, log(1e-5))^2
            float lsef = m0 + logf(s);
            const float lb = -11.512925464970229f;
            float mx = fmaxf(lsef, lb), mn = fminf(lsef, lb);
            float z = mx + log1pf(expf(mn - mx));
            zacc += z * z;
        }

        float mg = 3.4e38f;
#pragma unroll
        for (int p = 0; p < 8; ++p) mg = fminf(mg, tv[p] - tv[p + 1]);
        const size_t base = (size_t)row * TOPK;

        if (mg >= THR) {                 // unambiguous (normal path)
            float gs = 0.f;
#pragma unroll
            for (int p = 0; p < 8; ++p) gs += expf(tv[p] - m0);
            if (lane < 8) {
                float mytv = tv[0]; int myti = ti[0];
#pragma unroll
                for (int p = 1; p < 8; ++p)
                    if (lane == p) { mytv = tv[p]; myti = ti[p]; }
                out_idx[base + lane] = (float)myti;
                out_gate[base + lane] = expf(mytv - m0) / gs;
                atomicAdd(&fcnt_s[myti], 1.f);
            }
        } else {                         // inline fp64 recheck (~3.5% of rows)
            const bool cand = (lg >= tv[8] - THR);   // only these can be top-8
            unsigned long long cm = __ballot(cand);
            const float* xrw = x + (size_t)row * DDIM;
            float4 xv[8];
#pragma unroll
            for (int j = 0; j < 8; ++j)
                xv[j] = *reinterpret_cast<const float4*>(xrw + j * 256 + lane * 4);

            double myD = -HUGE_VAL;
            unsigned long long m2 = cm;
            while (m2) {                 // serial coalesced fp64 dots
                const int e = (int)__ffsll((unsigned long long)m2) - 1;
                m2 &= (m2 - 1);
                const float* wrp = W + (size_t)e * DDIM;
                double p0 = 0.0, p1 = 0.0, p2 = 0.0, p3 = 0.0;
#pragma unroll
                for (int j = 0; j < 8; ++j) {
                    float4 wv = *reinterpret_cast<const float4*>(wrp + j * 256 + lane * 4);
                    p0 = fma((double)xv[j].x, (double)wv.x, p0);
                    p1 = fma((double)xv[j].y, (double)wv.y, p1);
                    p2 = fma((double)xv[j].z, (double)wv.z, p2);
                    p3 = fma((double)xv[j].w, (double)wv.w, p3);
                }
                double sd = (p0 + p1) + (p2 + p3);
#pragma unroll
                for (int m = 1; m < 64; m <<= 1) sd += __shfl_xor(sd, m, 64);
                if (lane == e) myD = sd;
            }

            double v = cand ? myD : -HUGE_VAL;
            double tvd[8]; int ti8[8];
#pragma unroll
            for (int p = 0; p < 8; ++p) {
                double bv = v; int bgi = lane;
#pragma unroll
                for (int m = 1; m < 64; m <<= 1) {
                    double ov = __shfl_xor(bv, m, 64);
                    int ogi = __shfl_xor(bgi, m, 64);
                    if (ov > bv || (ov == bv && ogi < bgi)) { bv = ov; bgi = ogi; }
                }
                tvd[p] = bv; ti8[p] = bgi;
                if (lane == bgi) v = -HUGE_VAL;
            }
            const double m0d = tvd[0];
            double gsum = 0.0, ge[8];
#pragma unroll
            for (int j = 0; j < 8; ++j) { ge[j] = exp(tvd[j] - m0d); gsum += ge[j]; }
            if (lane < 8) {
                double myge = ge[0]; int myti = ti8[0];
#pragma unroll
                for (int j = 1; j < 8; ++j)
                    if (lane == j) { myge = ge[j]; myti = ti8[j]; }
                out_idx[base + lane] = (float)myti;
                out_gate[base + lane] = (float)(myge / gsum);
                atomicAdd(&fcnt_s[myti], 1.f);
            }
        }
    }

    // block-combine, then one global atomic per expert per block
    atomicAdd(&psum_s[lane], pcol);
    if (lane == 0) atomicAdd(&zsq_s, zacc);
    __syncthreads();
    if (tid < NEXP) {
        atomicAdd(&g_psum[tid], psum_s[tid]);
        atomicAdd(&g_freq[tid], fcnt_s[tid]);
    }
    if (tid == 0) atomicAdd(g_zsum, zsq_s);
}

__global__ void finalize_kernel(const float* __restrict__ g_psum,
                                const float* __restrict__ g_freq,
                                const float* __restrict__ g_zsum,
                                float* __restrict__ out_loss)
{
    const int lane = threadIdx.x & 63;
    float p = g_psum[lane], f = g_freq[lane];
    float sp = p, sf = f;
#pragma unroll
    for (int m = 1; m < 64; m <<= 1) { sp += __shfl_xor(sp, m, 64); sf += __shfl_xor(sf, m, 64); }
    sp = fmaxf(sp, 1e-12f);
    sf = fmaxf(sf, 1e-12f);
    float term = (p / sp) * (f / sf);
#pragma unroll
    for (int m = 1; m < 64; m <<= 1) term += __shfl_xor(term, m, 64);
    if (lane == 0)
        out_loss[0] = (float)NEXP * term + 0.1f * (g_zsum[0] / (float)NROWS);
}

extern "C" void kernel_launch(void* const* d_in, const int* in_sizes, int n_in,
                              void* d_out, int out_size, void* d_ws, size_t ws_size,
                              hipStream_t stream)
{
    const float* x = (const float*)d_in[0];
    const float* W = (const float*)d_in[1];
    float* out = (float*)d_out;
    float* out_idx  = out;                            // [65536*8] indices as float
    float* out_gate = out + (size_t)NROWS * TOPK;     // [65536*8] gates
    float* out_loss = out + (size_t)2 * NROWS * TOPK; // [1] loss

    // ws layout (floats): [0..63] psum | [64..127] freq | [128] zsum |
    //   [256..) logits 65536x64 (16 MB) | then wfrag (512 KB, 16B-aligned)
    float* acc    = (float*)d_ws;
    float* logits = (float*)d_ws + 256;
    short* wfrag  = (short*)((float*)d_ws + 256 + (size_t)NROWS * NEXP);
    hipMemsetAsync(d_ws, 0, 129 * sizeof(float), stream);

    prep_kernel<<<NSTEP, 256, 0, stream>>>(W, wfrag);
    gemm_kernel<<<NROWS / 64, 256, 0, stream>>>(x, wfrag, logits);
    epilogue_kernel<<<2048, 256, 0, stream>>>(x, W, logits, out_idx, out_gate,
                                              acc, acc + NEXP, acc + 2 * NEXP);
    finalize_kernel<<<1, 64, 0, stream>>>(acc, acc + NEXP, acc + 2 * NEXP, out_loss);
}

// Round 13
// 282.252 us; speedup vs baseline: 1.3309x; 1.2121x over previous
//
#include <hip/hip_runtime.h>
#include <math.h>

#define NROWS 65536
#define DDIM 2048
#define NEXP 64
#define TOPK 8

constexpr int NSTEP = 64;        // k-steps of 32
constexpr float THR = 3e-4f;     // ambiguity gap threshold (split-bf16 err rms ~4e-6)
constexpr int WFRAG_STEP = 4096; // shorts per k-step: [hl 2][ct 4][lane 64][j 8]

typedef short bf16x8 __attribute__((ext_vector_type(8)));
typedef float f32x4 __attribute__((ext_vector_type(4)));

__device__ inline unsigned short bfround(float f) {
    union { float f; unsigned u; } v; v.f = f;
    unsigned r = (v.u + 0x7fffu + ((v.u >> 16) & 1u)) >> 16;   // RNE
    return (unsigned short)r;
}
__device__ inline float bf2f(unsigned short h) {
    union { unsigned u; float f; } v; v.u = ((unsigned)h) << 16;
    return v.f;
}
__device__ inline void cvt8(const float4& A, const float4& B, bf16x8& h, bf16x8& l) {
    float f[8] = {A.x, A.y, A.z, A.w, B.x, B.y, B.z, B.w};
#pragma unroll
    for (int j = 0; j < 8; ++j) {
        unsigned short hh = bfround(f[j]);
        h[j] = (short)hh;
        l[j] = (short)bfround(f[j] - bf2f(hh));
    }
}

// One-shot: W fp32 [64][2048] -> bf16 hi/lo in MFMA B-fragment order.
__global__ __launch_bounds__(256)
void prep_kernel(const float* __restrict__ W, short* __restrict__ wfrag)
{
    const int t = blockIdx.x;           // 0..63
    const int tid = threadIdx.x;
    const int ct = tid >> 6, lane = tid & 63;
    const int e = ct * 16 + (lane & 15);
    const int k = t * 32 + (lane >> 4) * 8;
    const float* wp = W + (size_t)e * DDIM + k;
    float4 a = *reinterpret_cast<const float4*>(wp);
    float4 b = *reinterpret_cast<const float4*>(wp + 4);
    bf16x8 h, l;
    cvt8(a, b, h, l);
    short* base = wfrag + (size_t)t * WFRAG_STEP;
    *reinterpret_cast<bf16x8*>(base + (ct * 64 + lane) * 8) = h;          // hl=0
    *reinterpret_cast<bf16x8*>(base + 2048 + (ct * 64 + lane) * 8) = l;   // hl=1
}

// Split-bf16 MFMA GEMM (unchanged from r12 for attribution).
__global__ __launch_bounds__(256, 2)
void gemm_kernel(const float* __restrict__ x, const short* __restrict__ wfrag,
                 float* __restrict__ logits)
{
    __shared__ __align__(16) short Bfrag[2][2][4][64][8];   // 16 KB

    const int tid = threadIdx.x;
    const int w = tid >> 6;
    const int lane = tid & 63;
    const int g = lane >> 4;
    const int c = lane & 15;
    const int row0 = blockIdx.x * 64 + w * 16;
    const float* xr = x + (size_t)(row0 + c) * DDIM + g * 8;

    const int se = tid >> 2, skg = tid & 3;
    const int sct = se >> 4;
    const int slane = (se & 15) + (skg << 4);
    const int soff = (sct * 64 + slane) * 8;

    auto stageB = [&](int t, int buf) {
        const short* src = wfrag + (size_t)t * WFRAG_STEP + soff;
        *reinterpret_cast<bf16x8*>(&Bfrag[buf][0][sct][slane][0]) =
            *reinterpret_cast<const bf16x8*>(src);
        *reinterpret_cast<bf16x8*>(&Bfrag[buf][1][sct][slane][0]) =
            *reinterpret_cast<const bf16x8*>(src + 2048);
    };

    f32x4 acc[4];
#pragma unroll
    for (int ct = 0; ct < 4; ++ct) acc[ct] = (f32x4){0.f, 0.f, 0.f, 0.f};

    float4 xa0 = *reinterpret_cast<const float4*>(xr);
    float4 xa1 = *reinterpret_cast<const float4*>(xr + 4);
    float4 xb0, xb1;
    stageB(0, 0);
    __syncthreads();

    for (int t = 0; t < NSTEP; ++t) {
        const int buf = t & 1;
        const int kn = (t + 1) * 32;
        if (t + 1 < NSTEP) {
            xb0 = *reinterpret_cast<const float4*>(xr + kn);
            xb1 = *reinterpret_cast<const float4*>(xr + kn + 4);
            stageB(t + 1, buf ^ 1);
        }
        bf16x8 ah, al;
        cvt8(xa0, xa1, ah, al);
#pragma unroll
        for (int ct = 0; ct < 4; ++ct) {
            bf16x8 bh = *reinterpret_cast<const bf16x8*>(&Bfrag[buf][0][ct][lane][0]);
            bf16x8 bl = *reinterpret_cast<const bf16x8*>(&Bfrag[buf][1][ct][lane][0]);
            acc[ct] = __builtin_amdgcn_mfma_f32_16x16x32_bf16(ah, bh, acc[ct], 0, 0, 0);
            acc[ct] = __builtin_amdgcn_mfma_f32_16x16x32_bf16(ah, bl, acc[ct], 0, 0, 0);
            acc[ct] = __builtin_amdgcn_mfma_f32_16x16x32_bf16(al, bh, acc[ct], 0, 0, 0);
        }
        xa0 = xb0; xa1 = xb1;
        __syncthreads();
    }

#pragma unroll
    for (int ct = 0; ct < 4; ++ct)
#pragma unroll
        for (int reg = 0; reg < 4; ++reg)
            logits[(size_t)(row0 + g * 4 + reg) * NEXP + ct * 16 + c] = acc[ct][reg];
}

// Epilogue v2: one wave per row, full 64-lane BITONIC SORT on packed
// (value, 63-lane) u64 keys — descending order == lax.top_k order incl.
// lowest-index tie-break. 21 compare-exchanges vs the old 9x6=54 serial
// extraction (r12 post-mortem: extraction chain was the suspected sink).
// After sort, lane p holds rank p: gates/gaps via width-8 reduces.
__global__ __launch_bounds__(256, 2)
void epilogue_kernel(const float* __restrict__ x, const float* __restrict__ W,
                     const float* __restrict__ logits,
                     float* __restrict__ out_idx, float* __restrict__ out_gate,
                     float* __restrict__ g_psum, float* __restrict__ g_freq,
                     float* __restrict__ g_zsum)
{
    __shared__ float psum_s[NEXP];
    __shared__ float fcnt_s[NEXP];
    __shared__ float zsq_s;
    const int tid = threadIdx.x;
    const int w = tid >> 6;
    const int lane = tid & 63;
    if (tid < NEXP) { psum_s[tid] = 0.f; fcnt_s[tid] = 0.f; }
    if (tid == 0) zsq_s = 0.f;
    __syncthreads();

    const int wi = blockIdx.x * 4 + w;   // wave id 0..8191
    float pcol = 0.f, zacc = 0.f;

    for (int r8 = 0; r8 < 8; ++r8) {
        const int row = wi + r8 * 8192;
        const float lg = logits[(size_t)row * NEXP + lane];

        // pack: monotone f32 bits | (63 - lane)  (tie -> lower index wins)
        unsigned u = __float_as_uint(lg);
        unsigned ordb = (u & 0x80000000u) ? ~u : (u | 0x80000000u);
        unsigned long long key =
            ((unsigned long long)ordb << 32) | (unsigned)(63 - lane);

        // bitonic sort, descending (lane 0 = largest)
#pragma unroll
        for (int k = 2; k <= 64; k <<= 1) {
#pragma unroll
            for (int j = k >> 1; j > 0; j >>= 1) {
                unsigned long long other = __shfl_xor(key, j, 64);
                const bool keep_max = ((lane & j) == 0) == ((lane & k) == 0);
                const bool mine_bigger = key > other;
                key = (keep_max == mine_bigger) ? key : other;
            }
        }
        // decode rank-`lane` entry
        unsigned ou = (unsigned)(key >> 32);
        unsigned ub = (ou & 0x80000000u) ? (ou ^ 0x80000000u) : ~ou;
        const float val = __uint_as_float(ub);
        const int idxe = 63 - (int)(key & 63u);

        const float m0 = __shfl(val, 0, 64);

        // softmax over all 64 (original lane-local logit)
        float pe = expf(lg - m0);
        float s = pe;
#pragma unroll
        for (int m = 1; m < 64; m <<= 1) s += __shfl_xor(s, m, 64);
        pcol += pe / s;

        if (lane == 0) {   // z-loss: logaddexp(lse, log(1e-5))^2
            float lsef = m0 + logf(s);
            const float lb = -11.512925464970229f;
            float mx = fmaxf(lsef, lb), mn = fminf(lsef, lb);
            float z = mx + log1pf(expf(mn - mx));
            zacc += z * z;
        }

        // adjacent gaps among ranks 0..8
        float nxt = __shfl_down(val, 1, 64);
        float dg = (lane < 8) ? (val - nxt) : 3.4e38f;
        float mg = dg;
#pragma unroll
        for (int m = 1; m < 8; m <<= 1) mg = fminf(mg, __shfl_xor(mg, m, 8));
        mg = __shfl(mg, 0, 64);
        const float v9 = __shfl(val, 8, 64);
        const size_t base = (size_t)row * TOPK;

        if (mg >= THR) {                 // unambiguous: lane p<8 IS rank p
            float eg = expf(val - m0);
            float gs = eg;
#pragma unroll
            for (int m = 1; m < 8; m <<= 1) gs += __shfl_xor(gs, m, 8);
            if (lane < 8) {
                out_idx[base + lane] = (float)idxe;
                out_gate[base + lane] = eg / gs;
                atomicAdd(&fcnt_s[idxe], 1.f);
            }
        } else {                         // inline fp64 recheck (~3.5% of rows)
            const bool cand = (lg >= v9 - THR);
            unsigned long long cm = __ballot(cand);
            const float* xrw = x + (size_t)row * DDIM;
            float4 xv[8];
#pragma unroll
            for (int j = 0; j < 8; ++j)
                xv[j] = *reinterpret_cast<const float4*>(xrw + j * 256 + lane * 4);

            double myD = -HUGE_VAL;
            unsigned long long m2 = cm;
            while (m2) {                 // serial coalesced fp64 dots
                const int e = (int)__ffsll((unsigned long long)m2) - 1;
                m2 &= (m2 - 1);
                const float* wrp = W + (size_t)e * DDIM;
                double p0 = 0.0, p1 = 0.0, p2 = 0.0, p3 = 0.0;
#pragma unroll
                for (int j = 0; j < 8; ++j) {
                    float4 wv = *reinterpret_cast<const float4*>(wrp + j * 256 + lane * 4);
                    p0 = fma((double)xv[j].x, (double)wv.x, p0);
                    p1 = fma((double)xv[j].y, (double)wv.y, p1);
                    p2 = fma((double)xv[j].z, (double)wv.z, p2);
                    p3 = fma((double)xv[j].w, (double)wv.w, p3);
                }
                double sd = (p0 + p1) + (p2 + p3);
#pragma unroll
                for (int m = 1; m < 64; m <<= 1) sd += __shfl_xor(sd, m, 64);
                if (lane == e) myD = sd;
            }

            double v = cand ? myD : -HUGE_VAL;
            double tvd[8]; int ti8[8];
#pragma unroll
            for (int p = 0; p < 8; ++p) {
                double bv = v; int bgi = lane;
#pragma unroll
                for (int m = 1; m < 64; m <<= 1) {
                    double ov = __shfl_xor(bv, m, 64);
                    int ogi = __shfl_xor(bgi, m, 64);
                    if (ov > bv || (ov == bv && ogi < bgi)) { bv = ov; bgi = ogi; }
                }
                tvd[p] = bv; ti8[p] = bgi;
                if (lane == bgi) v = -HUGE_VAL;
            }
            const double m0d = tvd[0];
            double gsum = 0.0, ge[8];
#pragma unroll
            for (int j = 0; j < 8; ++j) { ge[j] = exp(tvd[j] - m0d); gsum += ge[j]; }
            if (lane < 8) {
                double myge = ge[0]; int myti = ti8[0];
#pragma unroll
                for (int j = 1; j < 8; ++j)
                    if (lane == j) { myge = ge[j]; myti = ti8[j]; }
                out_idx[base + lane] = (float)myti;
                out_gate[base + lane] = (float)(myge / gsum);
                atomicAdd(&fcnt_s[myti], 1.f);
            }
        }
    }

    // block-combine, then one global atomic per expert per block
    atomicAdd(&psum_s[lane], pcol);
    if (lane == 0) atomicAdd(&zsq_s, zacc);
    __syncthreads();
    if (tid < NEXP) {
        atomicAdd(&g_psum[tid], psum_s[tid]);
        atomicAdd(&g_freq[tid], fcnt_s[tid]);
    }
    if (tid == 0) atomicAdd(g_zsum, zsq_s);
}

__global__ void finalize_kernel(const float* __restrict__ g_psum,
                                const float* __restrict__ g_freq,
                                const float* __restrict__ g_zsum,
                                float* __restrict__ out_loss)
{
    const int lane = threadIdx.x & 63;
    float p = g_psum[lane], f = g_freq[lane];
    float sp = p, sf = f;
#pragma unroll
    for (int m = 1; m < 64; m <<= 1) { sp += __shfl_xor(sp, m, 64); sf += __shfl_xor(sf, m, 64); }
    sp = fmaxf(sp, 1e-12f);
    sf = fmaxf(sf, 1e-12f);
    float term = (p / sp) * (f / sf);
#pragma unroll
    for (int m = 1; m < 64; m <<= 1) term += __shfl_xor(term, m, 64);
    if (lane == 0)
        out_loss[0] = (float)NEXP * term + 0.1f * (g_zsum[0] / (float)NROWS);
}

extern "C" void kernel_launch(void* const* d_in, const int* in_sizes, int n_in,
                              void* d_out, int out_size, void* d_ws, size_t ws_size,
                              hipStream_t stream)
{
    const float* x = (const float*)d_in[0];
    const float* W = (const float*)d_in[1];
    float* out = (float*)d_out;
    float* out_idx  = out;                            // [65536*8] indices as float
    float* out_gate = out + (size_t)NROWS * TOPK;     // [65536*8] gates
    float* out_loss = out + (size_t)2 * NROWS * TOPK; // [1] loss

    // ws layout (floats): [0..63] psum | [64..127] freq | [128] zsum |
    //   [256..) logits 65536x64 (16 MB) | then wfrag (512 KB, 16B-aligned)
    float* acc    = (float*)d_ws;
    float* logits = (float*)d_ws + 256;
    short* wfrag  = (short*)((float*)d_ws + 256 + (size_t)NROWS * NEXP);
    hipMemsetAsync(d_ws, 0, 129 * sizeof(float), stream);

    prep_kernel<<<NSTEP, 256, 0, stream>>>(W, wfrag);
    gemm_kernel<<<NROWS / 64, 256, 0, stream>>>(x, wfrag, logits);
    epilogue_kernel<<<2048, 256, 0, stream>>>(x, W, logits, out_idx, out_gate,
                                              acc, acc + NEXP, acc + 2 * NEXP);
    finalize_kernel<<<1, 64, 0, stream>>>(acc, acc + NEXP, acc + 2 * NEXP, out_loss);
}